// Round 5
// baseline (2313.543 us; speedup 1.0000x reference)
//
#include <hip/hip_runtime.h>
#include <hip/hip_bf16.h>
#include <stdint.h>

// ---------------------------------------------------------------------------
// RNN_79164837199890: 2-layer LSTM (B=128,T=512,H=128) + policy/value heads.
// R5: single merged scan kernel. 32 WGs x 8 waves; waves 0-3 = L0 chunk,
// waves 4-7 = L1 same chunk one step behind; h0/h1 exchanged via LDS dbuf
// (513 barrier-steps for BOTH layers). L1 x-part (h0@W1x) in fp8 e4m3 to fit
// VGPR; recurrent paths stay bf16. 4-bit XOR slot swizzle on A-tiles.
// ---------------------------------------------------------------------------

typedef short v8s __attribute__((ext_vector_type(8)));   // 8 x bf16 fragment
typedef float v4f __attribute__((ext_vector_type(4)));   // MFMA accumulator

#define MFMA_B16(a,b,c) __builtin_amdgcn_mfma_f32_16x16x32_bf16((a),(b),(c),0,0,0)
#define MFMA_F8(a,b,c)  __builtin_amdgcn_mfma_f32_16x16x32_fp8_fp8((a),(b),(c),0,0,0)

#define NT     512
#define FIN    361
#define KP0    384        // padded K for layer-0 input GEMM
#define NPC    362
#define NPP    368

// workspace offsets (bytes)
#define OFF_Z    ((size_t)0)          // 65536*512*2 = 67108864 (z0x, gate-packed)
#define OFF_H1   ((size_t)83886080)   // 65536*128*2 = 16777216
#define OFF_W0XT ((size_t)100663296)  // 512*384*2 = 393216
#define OFF_WPT  ((size_t)101187584)  // 368*128*2 = 94208
#define OFF_B0P  ((size_t)101281792)  // 512*4 (pad 2048)
#define OFF_BPP  ((size_t)101285888)  // 368*4 (pad 2048)
#define OFF_ACC  ((size_t)101287936)  // 4 floats

static __device__ __forceinline__ short f2b(float f) {
  __hip_bfloat16 h = __float2bfloat16(f);
  union { __hip_bfloat16 h; short s; } cv; cv.h = h; return cv.s;
}
static __device__ __forceinline__ float b2f(unsigned int lo16) {
  union { unsigned u; float f; } cv; cv.u = lo16 << 16; return cv.f;
}
// f32 -> OCP e4m3fn with RNE (manual encode; |f| assumed < 448)
static __device__ __forceinline__ unsigned f2e4m3(float f) {
  union { float f; unsigned u; } cv; cv.f = f;
  unsigned s = (cv.u >> 31) << 7;
  float a = fabsf(f);
  a = fminf(a, 448.f);
  unsigned code;
  if (a >= 0.015625f) {                 // normal range: exp >= -6
    union { float f; unsigned u; } m; m.f = a;
    unsigned u = m.u + 0x7FFFF + ((m.u >> 20) & 1);   // RNE at 3 mantissa bits
    code = (u >> 20) - 960;             // rebias (127-7)<<3
    if (code > 126u) code = 126u;       // clamp to 448
  } else {                              // denormal: val = d * 2^-9
    code = (unsigned)rintf(a * 512.f);
  }
  return s | code;
}

// Raw barrier with LDS-only drain (global stores/loads keep floating).
static __device__ __forceinline__ void sync_lds() {
  __builtin_amdgcn_sched_barrier(0);
  asm volatile("s_waitcnt lgkmcnt(0)" ::: "memory");
  __builtin_amdgcn_s_barrier();
  __builtin_amdgcn_sched_barrier(0);
}

// --------------------------------------------------------------------------
// K0: weight conversion. Packed gate order: col' = m*4+g  <->  n = m + 128*g
// Forget-gate +1.0 folded into b0p. Zeroes accum.
// --------------------------------------------------------------------------
__global__ __launch_bounds__(256) void k_conv_weights(
    const float* __restrict__ W0, const float* __restrict__ b0,
    const float* __restrict__ Wp, const float* __restrict__ bp,
    char* __restrict__ ws) {
  int idx = blockIdx.x * 256 + threadIdx.x;
  __hip_bfloat16* W0xT = (__hip_bfloat16*)(ws + OFF_W0XT);
  __hip_bfloat16* WpT  = (__hip_bfloat16*)(ws + OFF_WPT);
  float* b0p = (float*)(ws + OFF_B0P);
  float* bpp = (float*)(ws + OFF_BPP);
  float* acc = (float*)(ws + OFF_ACC);

  if (idx < 196608) {                       // W0xT [512 cols'][384 k]
    int np = idx / 384, k = idx - np * 384;
    int n = (np >> 2) + 128 * (np & 3);
    float v = (k < FIN) ? W0[(size_t)k * 512 + n] : 0.f;
    W0xT[idx] = __float2bfloat16(v);
    return;
  }
  idx -= 196608;
  if (idx < 47104) {                        // WpT [368 p][128 k]
    int p = idx >> 7, k = idx & 127;
    WpT[idx] = __float2bfloat16(p < NPC ? Wp[(size_t)k * NPC + p] : 0.f);
    return;
  }
  idx -= 47104;
  if (idx < 512) {                          // b0p packed, +1.0 on forget gate
    int n = (idx >> 2) + 128 * (idx & 3);
    b0p[idx] = b0[n] + (((idx & 3) == 1) ? 1.0f : 0.0f);
    return;
  }
  idx -= 512;
  if (idx < NPP) { bpp[idx] = (idx < NPC) ? bp[idx] : -1e30f; return; }
  idx -= NPP;
  if (idx < 4) { acc[idx] = 0.f; return; }
}

// --------------------------------------------------------------------------
// K1: C[r, col'] = A[r,:] @ BT[col',:]^T + bias[col'],  C bf16 [65536][512]
// Tile 128x128, BK=64, 4 waves. AF32: A is f32 states with (b,t) remap and
// K-guard at 361.
// --------------------------------------------------------------------------
template<int KTOT, bool AF32>
__global__ __launch_bounds__(256) void k_gemm(
    const void* __restrict__ Ap, const __hip_bfloat16* __restrict__ BT,
    const float* __restrict__ bias, __hip_bfloat16* __restrict__ C) {
  __shared__ char sm[65536];                 // A: 2x16KB @0, B: 2x16KB @32768
  const int tid = threadIdx.x;
  const int l = tid & 63, wm = tid >> 6;
  const int c = l & 15, lg = l >> 4;
  const int m0 = blockIdx.x * 128;
  const int n0 = blockIdx.y * 128;
  constexpr int NS = KTOT / 64;

  uint4 ra[4], rb[4];
  float fa[32];

  auto LD = [&](int ks) {
#pragma unroll
    for (int i = 0; i < 4; i++) {
      int idx = i * 4096 + tid * 16;
      int row = idx >> 7, colb = idx & 127;
      if constexpr (AF32) {
        int r = m0 + row;
        const float* src = (const float*)Ap + ((size_t)(r & 127) * NT + (r >> 7)) * FIN;
        int kb = ks * 64 + (colb >> 1);
#pragma unroll
        for (int u = 0; u < 8; u++) {
          int kf = kb + u;
          fa[i * 8 + u] = (kf < FIN) ? src[kf] : 0.f;
        }
      } else {
        ra[i] = *(const uint4*)((const char*)Ap + ((size_t)(m0 + row) * KTOT + ks * 64) * 2 + colb);
      }
      rb[i] = *(const uint4*)((const char*)BT + ((size_t)(n0 + row) * KTOT + ks * 64) * 2 + colb);
    }
  };
  auto ST = [&](int bsel) {
#pragma unroll
    for (int i = 0; i < 4; i++) {
      int idx = i * 4096 + tid * 16;
      int row = idx >> 7, colb = idx & 127;
      int sw = colb ^ ((row & 7) << 4);
      if constexpr (AF32) {
        v8s w;
#pragma unroll
        for (int u = 0; u < 8; u++) w[u] = f2b(fa[i * 8 + u]);
        *(v8s*)(sm + bsel * 16384 + row * 128 + sw) = w;
      } else {
        *(uint4*)(sm + bsel * 16384 + row * 128 + sw) = ra[i];
      }
      *(uint4*)(sm + 32768 + bsel * 16384 + row * 128 + sw) = rb[i];
    }
  };

  v4f acc[2][8];
  v4f z4 = {0.f, 0.f, 0.f, 0.f};
#pragma unroll
  for (int mt = 0; mt < 2; mt++)
#pragma unroll
    for (int nt = 0; nt < 8; nt++) acc[mt][nt] = z4;

  LD(0); ST(0);
  __syncthreads();
  for (int ks = 0; ks < NS; ks++) {
    if (ks + 1 < NS) LD(ks + 1);
    const int bsel = ks & 1;
#pragma unroll
    for (int kk = 0; kk < 2; kk++) {
      int bir = kk * 64 + lg * 16;
      v8s af[2];
#pragma unroll
      for (int mt = 0; mt < 2; mt++) {
        int row = wm * 32 + mt * 16 + c;
        af[mt] = *(v8s*)(sm + bsel * 16384 + row * 128 + (bir ^ ((row & 7) << 4)));
      }
#pragma unroll
      for (int nt = 0; nt < 8; nt++) {
        int n = nt * 16 + c;
        v8s bf = *(v8s*)(sm + 32768 + bsel * 16384 + n * 128 + (bir ^ ((n & 7) << 4)));
#pragma unroll
        for (int mt = 0; mt < 2; mt++) acc[mt][nt] = MFMA_B16(af[mt], bf, acc[mt][nt]);
      }
    }
    if (ks + 1 < NS) ST((ks + 1) & 1);
    __syncthreads();
  }

#pragma unroll
  for (int mt = 0; mt < 2; mt++)
#pragma unroll
    for (int nt = 0; nt < 8; nt++) {
      int colp = n0 + nt * 16 + c;
      float bs = bias[colp];
#pragma unroll
      for (int j = 0; j < 4; j++) {
        int row = m0 + wm * 32 + mt * 16 + lg * 4 + j;
        C[(size_t)row * 512 + colp] = __float2bfloat16(acc[mt][nt][j] + bs);
      }
    }
}

// --------------------------------------------------------------------------
// K2: merged 2-layer scan. 32 WGs x 8 waves; chunk = 4 batch rows at M-rows
// {0,4,8,12} (1 valid row per lane-group). role = wv>>2: 0 -> L0 (h0(s)),
// 1 -> L1 (h1(s-1), x-part fp8 + h-part bf16). Each wave owns M-groups
// {rw, rw+4} -> 2 cells/lane. LDS: h0 bf16 dbuf @0, h1 bf16 dbuf @8192,
// h0 fp8 dbuf @16384 (total 20KB). One sync_lds() per step, 513 steps.
// A-tile layout: row*256B, 16B slot s stored at slot s^row (4-bit XOR).
// fp8 tile: row*128B, 8B slot s at s^row.
// --------------------------------------------------------------------------
__global__ __launch_bounds__(512, 2) void k_scan12(
    const __hip_bfloat16* __restrict__ Z, const float* __restrict__ W0f,
    const float* __restrict__ W1f, const float* __restrict__ b1,
    __hip_bfloat16* __restrict__ h1out) {
  __shared__ char sm[20480];
  const int tid = threadIdx.x;
  const int l = tid & 63, wv = tid >> 6;
  const int c = l & 15, lg = l >> 4;
  const int role = wv >> 2, rw = wv & 3;
  const int B0 = blockIdx.x * 4;
  const int m1 = 16 * rw + c, m2 = m1 + 64;

  // ---- weight fragments (register arrays shared across roles) ----
  // bregA: role0 -> W0h (rows FIN..FIN+127); role1 -> W1h (rows 128..255)
  const float* wsrcA = role ? (W1f + (size_t)128 * 512) : (W0f + (size_t)FIN * 512);
  v8s bregA[4][4][2];
  unsigned long long bregX[4][4][2];   // fp8-packed W1x (rows 0..127), used by role1
#pragma unroll
  for (int kk = 0; kk < 4; kk++)
#pragma unroll
    for (int g = 0; g < 4; g++)
#pragma unroll
      for (int u = 0; u < 2; u++) {
        int n = g * 128 + (u ? m2 : m1);
        v8s w;
        unsigned long long x = 0ull;
#pragma unroll
        for (int i = 0; i < 8; i++) {
          int k = kk * 32 + lg * 8 + i;
          w[i] = f2b(wsrcA[(size_t)k * 512 + n]);
          x |= (unsigned long long)f2e4m3(W1f[(size_t)k * 512 + n]) << (8 * i);
        }
        bregA[kk][g][u] = w;
        bregX[kk][g][u] = x;
      }

  float bq[4][2];
#pragma unroll
  for (int g = 0; g < 4; g++)
#pragma unroll
    for (int u = 0; u < 2; u++)
      bq[g][u] = role ? (b1[g * 128 + (u ? m2 : m1)] + ((g == 1) ? 1.0f : 0.0f)) : 0.0f;

  // zero all LDS state (h0(-1)=h1(-1)=0; junk A-rows stay 0 forever)
  for (int e = tid * 4; e < 20480; e += 512 * 4) *(int*)(sm + e) = 0;

  // z0 prefetch (role0 uses; 2 cells per lane)
  uint2 zA[2], zB[2], zC[2];
  auto ZLD = [&](int t, uint2* dst) {
#pragma unroll
    for (int u = 0; u < 2; u++)
      dst[u] = *(const uint2*)(Z + ((size_t)t * 128 + B0 + lg) * 512 + (u ? m2 : m1) * 4);
  };
  if (role == 0) { ZLD(0, zA); ZLD(1, zB); }

  float cst[2] = {0.f, 0.f};
  const int row = 4 * lg;
  __syncthreads();

  for (int s = 0; s <= NT; s++) {
    const bool active = role ? (s >= 1) : (s < NT);
    if (active) {
      // ---- A-tile read (bf16): role0 h0(s-1); role1 h1(s-2) ----
      const int abase = role ? (8192 + (s & 1) * 4096) : (((s + 1) & 1) * 4096);
      v8s aA[4];
#pragma unroll
      for (int kk = 0; kk < 4; kk++)
        aA[kk] = *(v8s*)(sm + abase + c * 256 + ((((kk * 4 + lg) ^ c) & 15) << 4));

      v4f acc[4][2];
#pragma unroll
      for (int g = 0; g < 4; g++)
#pragma unroll
        for (int u = 0; u < 2; u++)
          acc[g][u] = (v4f){bq[g][u], bq[g][u], bq[g][u], bq[g][u]};

#pragma unroll
      for (int kk = 0; kk < 4; kk++)
#pragma unroll
        for (int g = 0; g < 4; g++)
#pragma unroll
          for (int u = 0; u < 2; u++)
            acc[g][u] = MFMA_B16(aA[kk], bregA[kk][g][u], acc[g][u]);

      if (role) {                      // x-part: fp8 h0(s-1) @ fp8 W1x
        const int xbase = 16384 + ((s + 1) & 1) * 2048;
        long ax[4];
#pragma unroll
        for (int kk = 0; kk < 4; kk++)
          ax[kk] = *(const long*)(sm + xbase + c * 128 + ((((kk * 4 + lg) ^ c) & 15) << 3));
#pragma unroll
        for (int kk = 0; kk < 4; kk++)
#pragma unroll
          for (int g = 0; g < 4; g++)
#pragma unroll
            for (int u = 0; u < 2; u++)
              acc[g][u] = MFMA_F8(ax[kk], (long)bregX[kk][g][u], acc[g][u]);
      } else {
        if (s + 2 < NT) ZLD(s + 2, zC);
      }

      // ---- gates (2 cells/lane) ----
#pragma unroll
      for (int u = 0; u < 2; u++) {
        float xi = acc[0][u][0], xf = acc[1][u][0];
        float xg = acc[2][u][0], xo = acc[3][u][0];
        if (role == 0) {
          xi += b2f(zA[u].x & 0xffffu);
          xf += b2f(zA[u].x >> 16);          // +1.0 folded into b0p
          xg += b2f(zA[u].y & 0xffffu);
          xo += b2f(zA[u].y >> 16);
        }
        float ei = __expf(-xi);
        float ef = __expf(-xf);
        float eg = __expf(2.f * xg);
        float eo = __expf(-xo);
        float cn = cst[u] * __builtin_amdgcn_rcpf(1.f + ef)
                 + (eg - 1.f) * __builtin_amdgcn_rcpf((1.f + ei) * (eg + 1.f));
        cst[u] = cn;
        float ec = __expf(2.f * cn);
        float hv = (ec - 1.f) * __builtin_amdgcn_rcpf((1.f + eo) * (ec + 1.f));
        short hbits = f2b(hv);
        const int m = u ? m2 : m1;
        const int slot = (m >> 3) ^ row;
        if (role == 0) {
          *(short*)(sm + (s & 1) * 4096 + row * 256 + (slot << 4) + ((m * 2) & 15)) = hbits;
          *(unsigned char*)(sm + 16384 + (s & 1) * 2048 + row * 128 + (slot << 3) + (m & 7)) =
              (unsigned char)f2e4m3(hv);
        } else {
          *(short*)(sm + 8192 + ((s + 1) & 1) * 4096 + row * 256 + (slot << 4) + ((m * 2) & 15)) = hbits;
          union { short s; __hip_bfloat16 h; } cv; cv.s = hbits;
          h1out[((size_t)(s - 1) * 128 + B0 + lg) * 128 + m] = cv.h;
        }
      }
      if (role == 0) {
#pragma unroll
        for (int u = 0; u < 2; u++) { zA[u] = zB[u]; zB[u] = zC[u]; }
      }
    }
    sync_lds();
  }
}

// --------------------------------------------------------------------------
// K5: heads. WG = 64 rows (4 waves x 16). Logits GEMM [64x128]@[128x368] then
// per-row softmax/xent/argmax + value head; atomic partial sums.
// --------------------------------------------------------------------------
__global__ __launch_bounds__(256) void k_heads(
    const __hip_bfloat16* __restrict__ Hh, const __hip_bfloat16* __restrict__ WpT,
    const float* __restrict__ bpp, const float* __restrict__ Wv,
    const float* __restrict__ bv, const int* __restrict__ moves,
    const float* __restrict__ values, float* __restrict__ accum) {
  __shared__ char sm[110592];                // A 16KB @0, B 94208B @16384
  const int tid = threadIdx.x;
  const int l = tid & 63, wm = tid >> 6;
  const int c = l & 15, lg = l >> 4;
  const int r0 = blockIdx.x * 64;

#pragma unroll
  for (int i = 0; i < 4; i++) {
    int idx = i * 4096 + tid * 16;
    int row = idx >> 8, colb = idx & 255;
    uint4 v = *(const uint4*)((const char*)Hh + (size_t)r0 * 256 + idx);
    *(uint4*)(sm + row * 256 + (colb ^ ((row & 7) << 4))) = v;
  }
#pragma unroll
  for (int i = 0; i < 23; i++) {
    int idx = i * 4096 + tid * 16;
    int row = idx >> 8, colb = idx & 255;
    uint4 v = *(const uint4*)((const char*)WpT + idx);
    *(uint4*)(sm + 16384 + row * 256 + (colb ^ ((row & 7) << 4))) = v;
  }
  __syncthreads();

  v4f acc[23];
  v4f z4 = {0.f, 0.f, 0.f, 0.f};
#pragma unroll
  for (int q = 0; q < 23; q++) acc[q] = z4;
#pragma unroll
  for (int kk = 0; kk < 4; kk++) {
    int bir = kk * 64 + lg * 16;
    int ar = wm * 16 + c;
    v8s a = *(v8s*)(sm + ar * 256 + (bir ^ ((ar & 7) << 4)));
#pragma unroll
    for (int q = 0; q < 23; q++) {
      int n = q * 16 + c;
      v8s b = *(v8s*)(sm + 16384 + n * 256 + (bir ^ ((n & 7) << 4)));
      acc[q] = MFMA_B16(a, b, acc[q]);
    }
  }
  float bq[23];
#pragma unroll
  for (int q = 0; q < 23; q++) bq[q] = bpp[q * 16 + c];

  float tp = 0.f, tv = 0.f, ta = 0.f, tn = 0.f;
#pragma unroll
  for (int j = 0; j < 4; j++) {
    int rloc = lg * 4 + j;
    int r = r0 + wm * 16 + rloc;
    int t = r >> 7, b = r & 127;
    int mv = moves[(size_t)b * NT + t];
    float val = values[(size_t)b * NT + t];
    float msk = (val != -9.0f) ? 1.f : 0.f;

    float pmax = -3.0e38f;
#pragma unroll
    for (int q = 0; q < 23; q++) pmax = fmaxf(pmax, acc[q][j] + bq[q]);
#pragma unroll
    for (int d = 1; d < 16; d <<= 1) pmax = fmaxf(pmax, __shfl_xor(pmax, d, 64));
    float ps = 0.f;
#pragma unroll
    for (int q = 0; q < 23; q++) ps += __expf((acc[q][j] + bq[q]) - pmax);
#pragma unroll
    for (int d = 1; d < 16; d <<= 1) ps += __shfl_xor(ps, d, 64);
    float lse = pmax + __logf(ps);

    int qm = mv >> 4, cm = mv & 15;
    float mlv = 0.f;
#pragma unroll
    for (int q = 0; q < 23; q++) if (q == qm) mlv = acc[q][j] + bq[q];
    mlv = __shfl(mlv, (l & 48) + cm, 64);
    float xent = lse - mlv;

    float amx = -3.0e38f; int aix = 0;
#pragma unroll
    for (int q = 0; q < 23; q++) {
      float v = acc[q][j] + bq[q];
      if (v > amx) { amx = v; aix = q * 16 + c; }
    }
#pragma unroll
    for (int d = 1; d < 16; d <<= 1) {
      float ov = __shfl_xor(amx, d, 64);
      int oi = __shfl_xor(aix, d, 64);
      if (ov > amx || (ov == amx && oi < aix)) { amx = ov; aix = oi; }
    }

    float pd = 0.f;
    int vrow = wm * 16 + rloc;
#pragma unroll
    for (int i = 0; i < 8; i++) {
      int k = c * 8 + i;
      short hv = *(short*)(sm + vrow * 256 + ((k * 2) ^ ((vrow & 7) << 4)));
      pd += b2f((unsigned short)hv) * Wv[k];
    }
#pragma unroll
    for (int d = 1; d < 16; d <<= 1) pd += __shfl_xor(pd, d, 64);
    float eo = __expf(2.f * (pd + bv[0]));
    float win = (eo - 1.f) * __builtin_amdgcn_rcpf(eo + 1.f);
    float dv = win - val;

    if (c == 0) {
      tp += msk * xent;
      tv += msk * dv * dv;
      ta += (aix == mv) ? 1.f : 0.f;
      tn += msk;
    }
  }
  tp += __shfl_xor(tp, 16, 64); tp += __shfl_xor(tp, 32, 64);
  tv += __shfl_xor(tv, 16, 64); tv += __shfl_xor(tv, 32, 64);
  ta += __shfl_xor(ta, 16, 64); ta += __shfl_xor(ta, 32, 64);
  tn += __shfl_xor(tn, 16, 64); tn += __shfl_xor(tn, 32, 64);
  if (l == 0) {
    atomicAdd(accum + 0, tp);
    atomicAdd(accum + 1, tv);
    atomicAdd(accum + 2, ta);
    atomicAdd(accum + 3, tn);
  }
}

__global__ void k_final(const float* __restrict__ accum, float* __restrict__ out) {
  if (threadIdx.x == 0) {
    float nm = accum[3];
    out[0] = accum[0] / nm;
    out[1] = accum[1] / nm;
    out[2] = accum[2] / 65536.0f;
  }
}

// --------------------------------------------------------------------------
extern "C" void kernel_launch(void* const* d_in, const int* in_sizes, int n_in,
                              void* d_out, int out_size, void* d_ws, size_t ws_size,
                              hipStream_t stream) {
  (void)in_sizes; (void)n_in; (void)out_size; (void)ws_size;
  const float* states = (const float*)d_in[0];
  const int*   moves  = (const int*)d_in[1];
  const float* values = (const float*)d_in[2];
  const float* W0 = (const float*)d_in[3];
  const float* b0 = (const float*)d_in[4];
  const float* W1 = (const float*)d_in[5];
  const float* b1 = (const float*)d_in[6];
  const float* Wp = (const float*)d_in[7];
  const float* bp = (const float*)d_in[8];
  const float* Wv = (const float*)d_in[9];
  const float* bv = (const float*)d_in[10];
  char* ws = (char*)d_ws;

  __hip_bfloat16* zbuf = (__hip_bfloat16*)(ws + OFF_Z);
  __hip_bfloat16* h1   = (__hip_bfloat16*)(ws + OFF_H1);
  __hip_bfloat16* W0xT = (__hip_bfloat16*)(ws + OFF_W0XT);
  __hip_bfloat16* WpT  = (__hip_bfloat16*)(ws + OFF_WPT);
  float* b0p = (float*)(ws + OFF_B0P);
  float* bpp = (float*)(ws + OFF_BPP);
  float* acc = (float*)(ws + OFF_ACC);

  k_conv_weights<<<956, 256, 0, stream>>>(W0, b0, Wp, bp, ws);
  k_gemm<KP0, true><<<dim3(512, 4), 256, 0, stream>>>(states, W0xT, b0p, zbuf);
  k_scan12<<<32, 512, 0, stream>>>(zbuf, W0, W1, b1, h1);
  k_heads<<<1024, 256, 0, stream>>>(h1, WpT, bpp, Wv, bv, moves, values, acc);
  k_final<<<1, 1, 0, stream>>>(acc, (float*)d_out);
}

// Round 6
// 1034.359 us; speedup vs baseline: 2.2367x; 2.2367x over previous
//
#include <hip/hip_runtime.h>
#include <hip/hip_bf16.h>
#include <stdint.h>

// ---------------------------------------------------------------------------
// RNN_79164837199890: 2-layer LSTM (B=128,T=512,H=128) + policy/value heads.
// R6: merged scan, spill-free geometry. 32 WGs x 16 waves (1024 thr);
// waves 0-7 = L0 (W0h bf16, 64 VGPR), waves 8-15 = L1 (W1h+W1x fp8, 64 VGPR);
// weight build inside role branches so exclusive lifetimes share registers.
// h0/h1 exchanged via LDS dbuf only (no h0 global). One barrier per step.
// ---------------------------------------------------------------------------

typedef short v8s __attribute__((ext_vector_type(8)));   // 8 x bf16 fragment
typedef float v4f __attribute__((ext_vector_type(4)));   // MFMA accumulator

#define MFMA_B16(a,b,c) __builtin_amdgcn_mfma_f32_16x16x32_bf16((a),(b),(c),0,0,0)
#define MFMA_F8(a,b,c)  __builtin_amdgcn_mfma_f32_16x16x32_fp8_fp8((a),(b),(c),0,0,0)

#define NT     512
#define FIN    361
#define KP0    384        // padded K for layer-0 input GEMM
#define NPC    362
#define NPP    368

// workspace offsets (bytes)
#define OFF_Z    ((size_t)0)          // 65536*512*2 = 67108864 (z0x, gate-packed)
#define OFF_H1   ((size_t)83886080)   // 65536*128*2 = 16777216
#define OFF_W0XT ((size_t)100663296)  // 512*384*2 = 393216
#define OFF_WPT  ((size_t)101187584)  // 368*128*2 = 94208
#define OFF_B0P  ((size_t)101281792)  // 512*4 (pad 2048)
#define OFF_BPP  ((size_t)101285888)  // 368*4 (pad 2048)
#define OFF_ACC  ((size_t)101287936)  // 4 floats

static __device__ __forceinline__ short f2b(float f) {
  __hip_bfloat16 h = __float2bfloat16(f);
  union { __hip_bfloat16 h; short s; } cv; cv.h = h; return cv.s;
}
static __device__ __forceinline__ float b2f(unsigned int lo16) {
  union { unsigned u; float f; } cv; cv.u = lo16 << 16; return cv.f;
}
// f32 -> OCP e4m3fn with RNE (manual encode; |f| assumed < 448)
static __device__ __forceinline__ unsigned f2e4m3(float f) {
  union { float f; unsigned u; } cv; cv.f = f;
  unsigned s = (cv.u >> 31) << 7;
  float a = fabsf(f);
  a = fminf(a, 448.f);
  unsigned code;
  if (a >= 0.015625f) {                 // normal range: exp >= -6
    union { float f; unsigned u; } m; m.f = a;
    unsigned u = m.u + 0x7FFFF + ((m.u >> 20) & 1);   // RNE at 3 mantissa bits
    code = (u >> 20) - 960;             // rebias (127-7)<<3
    if (code > 126u) code = 126u;       // clamp to 448
  } else {                              // denormal: val = d * 2^-9
    code = (unsigned)rintf(a * 512.f);
  }
  return s | code;
}

// Raw barrier with LDS-only drain (global stores/loads keep floating).
static __device__ __forceinline__ void sync_lds() {
  __builtin_amdgcn_sched_barrier(0);
  asm volatile("s_waitcnt lgkmcnt(0)" ::: "memory");
  __builtin_amdgcn_s_barrier();
  __builtin_amdgcn_sched_barrier(0);
}

// --------------------------------------------------------------------------
// K0: weight conversion. Packed gate order: col' = m*4+g  <->  n = m + 128*g
// Forget-gate +1.0 folded into b0p. Zeroes accum.
// --------------------------------------------------------------------------
__global__ __launch_bounds__(256) void k_conv_weights(
    const float* __restrict__ W0, const float* __restrict__ b0,
    const float* __restrict__ Wp, const float* __restrict__ bp,
    char* __restrict__ ws) {
  int idx = blockIdx.x * 256 + threadIdx.x;
  __hip_bfloat16* W0xT = (__hip_bfloat16*)(ws + OFF_W0XT);
  __hip_bfloat16* WpT  = (__hip_bfloat16*)(ws + OFF_WPT);
  float* b0p = (float*)(ws + OFF_B0P);
  float* bpp = (float*)(ws + OFF_BPP);
  float* acc = (float*)(ws + OFF_ACC);

  if (idx < 196608) {                       // W0xT [512 cols'][384 k]
    int np = idx / 384, k = idx - np * 384;
    int n = (np >> 2) + 128 * (np & 3);
    float v = (k < FIN) ? W0[(size_t)k * 512 + n] : 0.f;
    W0xT[idx] = __float2bfloat16(v);
    return;
  }
  idx -= 196608;
  if (idx < 47104) {                        // WpT [368 p][128 k]
    int p = idx >> 7, k = idx & 127;
    WpT[idx] = __float2bfloat16(p < NPC ? Wp[(size_t)k * NPC + p] : 0.f);
    return;
  }
  idx -= 47104;
  if (idx < 512) {                          // b0p packed, +1.0 on forget gate
    int n = (idx >> 2) + 128 * (idx & 3);
    b0p[idx] = b0[n] + (((idx & 3) == 1) ? 1.0f : 0.0f);
    return;
  }
  idx -= 512;
  if (idx < NPP) { bpp[idx] = (idx < NPC) ? bp[idx] : -1e30f; return; }
  idx -= NPP;
  if (idx < 4) { acc[idx] = 0.f; return; }
}

// --------------------------------------------------------------------------
// K1: C[r, col'] = A[r,:] @ BT[col',:]^T + bias[col'],  C bf16 [65536][512]
// Tile 128x128, BK=64, 4 waves. AF32: A is f32 states with (b,t) remap and
// K-guard at 361.
// --------------------------------------------------------------------------
template<int KTOT, bool AF32>
__global__ __launch_bounds__(256) void k_gemm(
    const void* __restrict__ Ap, const __hip_bfloat16* __restrict__ BT,
    const float* __restrict__ bias, __hip_bfloat16* __restrict__ C) {
  __shared__ char sm[65536];                 // A: 2x16KB @0, B: 2x16KB @32768
  const int tid = threadIdx.x;
  const int l = tid & 63, wm = tid >> 6;
  const int c = l & 15, lg = l >> 4;
  const int m0 = blockIdx.x * 128;
  const int n0 = blockIdx.y * 128;
  constexpr int NS = KTOT / 64;

  uint4 ra[4], rb[4];
  float fa[32];

  auto LD = [&](int ks) {
#pragma unroll
    for (int i = 0; i < 4; i++) {
      int idx = i * 4096 + tid * 16;
      int row = idx >> 7, colb = idx & 127;
      if constexpr (AF32) {
        int r = m0 + row;
        const float* src = (const float*)Ap + ((size_t)(r & 127) * NT + (r >> 7)) * FIN;
        int kb = ks * 64 + (colb >> 1);
#pragma unroll
        for (int u = 0; u < 8; u++) {
          int kf = kb + u;
          fa[i * 8 + u] = (kf < FIN) ? src[kf] : 0.f;
        }
      } else {
        ra[i] = *(const uint4*)((const char*)Ap + ((size_t)(m0 + row) * KTOT + ks * 64) * 2 + colb);
      }
      rb[i] = *(const uint4*)((const char*)BT + ((size_t)(n0 + row) * KTOT + ks * 64) * 2 + colb);
    }
  };
  auto ST = [&](int bsel) {
#pragma unroll
    for (int i = 0; i < 4; i++) {
      int idx = i * 4096 + tid * 16;
      int row = idx >> 7, colb = idx & 127;
      int sw = colb ^ ((row & 7) << 4);
      if constexpr (AF32) {
        v8s w;
#pragma unroll
        for (int u = 0; u < 8; u++) w[u] = f2b(fa[i * 8 + u]);
        *(v8s*)(sm + bsel * 16384 + row * 128 + sw) = w;
      } else {
        *(uint4*)(sm + bsel * 16384 + row * 128 + sw) = ra[i];
      }
      *(uint4*)(sm + 32768 + bsel * 16384 + row * 128 + sw) = rb[i];
    }
  };

  v4f acc[2][8];
  v4f z4 = {0.f, 0.f, 0.f, 0.f};
#pragma unroll
  for (int mt = 0; mt < 2; mt++)
#pragma unroll
    for (int nt = 0; nt < 8; nt++) acc[mt][nt] = z4;

  LD(0); ST(0);
  __syncthreads();
  for (int ks = 0; ks < NS; ks++) {
    if (ks + 1 < NS) LD(ks + 1);
    const int bsel = ks & 1;
#pragma unroll
    for (int kk = 0; kk < 2; kk++) {
      int bir = kk * 64 + lg * 16;
      v8s af[2];
#pragma unroll
      for (int mt = 0; mt < 2; mt++) {
        int row = wm * 32 + mt * 16 + c;
        af[mt] = *(v8s*)(sm + bsel * 16384 + row * 128 + (bir ^ ((row & 7) << 4)));
      }
#pragma unroll
      for (int nt = 0; nt < 8; nt++) {
        int n = nt * 16 + c;
        v8s bf = *(v8s*)(sm + 32768 + bsel * 16384 + n * 128 + (bir ^ ((n & 7) << 4)));
#pragma unroll
        for (int mt = 0; mt < 2; mt++) acc[mt][nt] = MFMA_B16(af[mt], bf, acc[mt][nt]);
      }
    }
    if (ks + 1 < NS) ST((ks + 1) & 1);
    __syncthreads();
  }

#pragma unroll
  for (int mt = 0; mt < 2; mt++)
#pragma unroll
    for (int nt = 0; nt < 8; nt++) {
      int colp = n0 + nt * 16 + c;
      float bs = bias[colp];
#pragma unroll
      for (int j = 0; j < 4; j++) {
        int row = m0 + wm * 32 + mt * 16 + lg * 4 + j;
        C[(size_t)row * 512 + colp] = __float2bfloat16(acc[mt][nt][j] + bs);
      }
    }
}

// --------------------------------------------------------------------------
// K2: merged 2-layer scan, spill-free. 32 WGs x 16 waves (1024 thr).
// chunk = 4 batch rows at M-rows {0,4,8,12}. role = wv>>3 (0: L0, 1: L1 one
// step behind). Wave rw owns hidden m in [16rw,16rw+16); lane (c,lg):
// m=16rw+c, batch=B0+lg (M-row 4lg). 1 cell/lane.
// LDS: h0 bf16 dbuf @0 (2x4KB), h0 fp8 dbuf @8192 (2x2KB),
//      h1 fp8 dbuf @12288 (2x2KB). 4-bit XOR slot swizzle everywhere.
// role1: z1 = h0@W1x (fp8) + h1@W1h (fp8) + b1 in-MFMA.
// --------------------------------------------------------------------------
__global__ __launch_bounds__(1024, 4) void k_scan12(
    const __hip_bfloat16* __restrict__ Z, const float* __restrict__ W0f,
    const float* __restrict__ W1f, const float* __restrict__ b1,
    __hip_bfloat16* __restrict__ h1out) {
  __shared__ char sm[16384];
  const int tid = threadIdx.x;
  const int l = tid & 63, wv = tid >> 6;
  const int c = l & 15, lg = l >> 4;
  const int role = wv >> 3, rw = wv & 7;
  const int B0 = blockIdx.x * 4;
  const int m_ = 16 * rw + c;
  const int row = 4 * lg;                    // M-row this lane's cell lives at
  v4f z4 = {0.f, 0.f, 0.f, 0.f};

  // zero all LDS state (h0(-1)=h1(-1)=0; junk M-rows stay 0 forever)
  for (int e = tid * 4; e < 16384; e += 1024 * 4) *(int*)(sm + e) = 0;

  if (role == 0) {
    // ================= L0 =================
    v8s breg[4][4];                          // W0h bf16 B-frags (64 VGPR)
#pragma unroll
    for (int kk = 0; kk < 4; kk++)
#pragma unroll
      for (int g = 0; g < 4; g++) {
        int n = g * 128 + m_;
        v8s w;
#pragma unroll
        for (int i = 0; i < 8; i++)
          w[i] = f2b(W0f[(size_t)(FIN + kk * 32 + lg * 8 + i) * 512 + n]);
        breg[kk][g] = w;
      }

    uint2 zA, zB, zC;
    auto ZLD = [&](int t) -> uint2 {
      return *(const uint2*)(Z + ((size_t)t * 128 + B0 + lg) * 512 + m_ * 4);
    };
    zA = ZLD(0); zB = ZLD(1);
    float cst = 0.f;
    // write offsets (slot-swizzled)
    const int wb16 = row * 256 + (((m_ >> 3) ^ row) << 4) + ((m_ * 2) & 15);
    const int wf8  = row * 128 + (((m_ >> 3) ^ row) << 3) + (m_ & 7);
    __syncthreads();

    for (int s = 0; s < NT; s++) {
      const int abase = ((s + 1) & 1) * 4096;          // h0(s-1) bf16
      v4f acc[4];
#pragma unroll
      for (int g = 0; g < 4; g++) acc[g] = z4;
#pragma unroll
      for (int kk = 0; kk < 4; kk++) {
        v8s a = *(v8s*)(sm + abase + c * 256 + ((((kk * 4 + lg) ^ c) & 15) << 4));
#pragma unroll
        for (int g = 0; g < 4; g++) acc[g] = MFMA_B16(a, breg[kk][g], acc[g]);
      }
      if (s + 2 < NT) zC = ZLD(s + 2);

      float xi = acc[0][0] + b2f(zA.x & 0xffffu);
      float xf = acc[1][0] + b2f(zA.x >> 16);          // +1.0 folded into b0p
      float xg = acc[2][0] + b2f(zA.y & 0xffffu);
      float xo = acc[3][0] + b2f(zA.y >> 16);
      float ei = __expf(-xi);
      float ef = __expf(-xf);
      float eg = __expf(2.f * xg);
      float eo = __expf(-xo);
      float cn = cst * __builtin_amdgcn_rcpf(1.f + ef)
               + (eg - 1.f) * __builtin_amdgcn_rcpf((1.f + ei) * (eg + 1.f));
      cst = cn;
      float ec = __expf(2.f * cn);
      float hv = (ec - 1.f) * __builtin_amdgcn_rcpf((1.f + eo) * (ec + 1.f));
      *(short*)(sm + (s & 1) * 4096 + wb16) = f2b(hv);
      *(unsigned char*)(sm + 8192 + (s & 1) * 2048 + wf8) = (unsigned char)f2e4m3(hv);
      zA = zB; zB = zC;
      sync_lds();
    }
    sync_lds();                                        // s = NT (L1 tail step)
  } else {
    // ================= L1 (one step behind) =================
    unsigned long long bregH[4][4], bregX[4][4];       // fp8 B-frags (64 VGPR)
#pragma unroll
    for (int kk = 0; kk < 4; kk++)
#pragma unroll
      for (int g = 0; g < 4; g++) {
        int n = g * 128 + m_;
        unsigned long long wh = 0ull, wx = 0ull;
#pragma unroll
        for (int i = 0; i < 8; i++) {
          int k = kk * 32 + lg * 8 + i;
          wh |= (unsigned long long)f2e4m3(W1f[(size_t)(128 + k) * 512 + n]) << (8 * i);
          wx |= (unsigned long long)f2e4m3(W1f[(size_t)k * 512 + n]) << (8 * i);
        }
        bregH[kk][g] = wh;
        bregX[kk][g] = wx;
      }
    float bq[4];
#pragma unroll
    for (int g = 0; g < 4; g++)
      bq[g] = b1[g * 128 + m_] + ((g == 1) ? 1.0f : 0.0f);
    float cst = 0.f;
    const int wf8 = row * 128 + (((m_ >> 3) ^ row) << 3) + (m_ & 7);
    __syncthreads();
    sync_lds();                                        // skip s=0 (idle)

    for (int s = 1; s <= NT; s++) {
      const int hbase = 12288 + (s & 1) * 2048;        // h1(s-2) fp8
      const int xbase = 8192 + ((s + 1) & 1) * 2048;   // h0(s-1) fp8
      v4f acc[4];
#pragma unroll
      for (int g = 0; g < 4; g++) acc[g] = (v4f){bq[g], bq[g], bq[g], bq[g]};
#pragma unroll
      for (int kk = 0; kk < 4; kk++) {
        long ah = *(const long*)(sm + hbase + c * 128 + ((((kk * 4 + lg) ^ c) & 15) << 3));
#pragma unroll
        for (int g = 0; g < 4; g++) acc[g] = MFMA_F8(ah, (long)bregH[kk][g], acc[g]);
      }
#pragma unroll
      for (int kk = 0; kk < 4; kk++) {
        long ax = *(const long*)(sm + xbase + c * 128 + ((((kk * 4 + lg) ^ c) & 15) << 3));
#pragma unroll
        for (int g = 0; g < 4; g++) acc[g] = MFMA_F8(ax, (long)bregX[kk][g], acc[g]);
      }

      float xi = acc[0][0], xf = acc[1][0], xg = acc[2][0], xo = acc[3][0];
      float ei = __expf(-xi);
      float ef = __expf(-xf);
      float eg = __expf(2.f * xg);
      float eo = __expf(-xo);
      float cn = cst * __builtin_amdgcn_rcpf(1.f + ef)
               + (eg - 1.f) * __builtin_amdgcn_rcpf((1.f + ei) * (eg + 1.f));
      cst = cn;
      float ec = __expf(2.f * cn);
      float hv = (ec - 1.f) * __builtin_amdgcn_rcpf((1.f + eo) * (ec + 1.f));
      short hbits = f2b(hv);
      *(unsigned char*)(sm + 12288 + ((s + 1) & 1) * 2048 + wf8) =
          (unsigned char)f2e4m3(hv);
      union { short s; __hip_bfloat16 h; } cv; cv.s = hbits;
      h1out[((size_t)(s - 1) * 128 + B0 + lg) * 128 + m_] = cv.h;
      sync_lds();
    }
  }
}

// --------------------------------------------------------------------------
// K5: heads. WG = 64 rows (4 waves x 16). Logits GEMM [64x128]@[128x368] then
// per-row softmax/xent/argmax + value head; atomic partial sums.
// --------------------------------------------------------------------------
__global__ __launch_bounds__(256) void k_heads(
    const __hip_bfloat16* __restrict__ Hh, const __hip_bfloat16* __restrict__ WpT,
    const float* __restrict__ bpp, const float* __restrict__ Wv,
    const float* __restrict__ bv, const int* __restrict__ moves,
    const float* __restrict__ values, float* __restrict__ accum) {
  __shared__ char sm[110592];                // A 16KB @0, B 94208B @16384
  const int tid = threadIdx.x;
  const int l = tid & 63, wm = tid >> 6;
  const int c = l & 15, lg = l >> 4;
  const int r0 = blockIdx.x * 64;

#pragma unroll
  for (int i = 0; i < 4; i++) {
    int idx = i * 4096 + tid * 16;
    int row = idx >> 8, colb = idx & 255;
    uint4 v = *(const uint4*)((const char*)Hh + (size_t)r0 * 256 + idx);
    *(uint4*)(sm + row * 256 + (colb ^ ((row & 7) << 4))) = v;
  }
#pragma unroll
  for (int i = 0; i < 23; i++) {
    int idx = i * 4096 + tid * 16;
    int row = idx >> 8, colb = idx & 255;
    uint4 v = *(const uint4*)((const char*)WpT + idx);
    *(uint4*)(sm + 16384 + row * 256 + (colb ^ ((row & 7) << 4))) = v;
  }
  __syncthreads();

  v4f acc[23];
  v4f z4 = {0.f, 0.f, 0.f, 0.f};
#pragma unroll
  for (int q = 0; q < 23; q++) acc[q] = z4;
#pragma unroll
  for (int kk = 0; kk < 4; kk++) {
    int bir = kk * 64 + lg * 16;
    int ar = wm * 16 + c;
    v8s a = *(v8s*)(sm + ar * 256 + (bir ^ ((ar & 7) << 4)));
#pragma unroll
    for (int q = 0; q < 23; q++) {
      int n = q * 16 + c;
      v8s b = *(v8s*)(sm + 16384 + n * 256 + (bir ^ ((n & 7) << 4)));
      acc[q] = MFMA_B16(a, b, acc[q]);
    }
  }
  float bq[23];
#pragma unroll
  for (int q = 0; q < 23; q++) bq[q] = bpp[q * 16 + c];

  float tp = 0.f, tv = 0.f, ta = 0.f, tn = 0.f;
#pragma unroll
  for (int j = 0; j < 4; j++) {
    int rloc = lg * 4 + j;
    int r = r0 + wm * 16 + rloc;
    int t = r >> 7, b = r & 127;
    int mv = moves[(size_t)b * NT + t];
    float val = values[(size_t)b * NT + t];
    float msk = (val != -9.0f) ? 1.f : 0.f;

    float pmax = -3.0e38f;
#pragma unroll
    for (int q = 0; q < 23; q++) pmax = fmaxf(pmax, acc[q][j] + bq[q]);
#pragma unroll
    for (int d = 1; d < 16; d <<= 1) pmax = fmaxf(pmax, __shfl_xor(pmax, d, 64));
    float ps = 0.f;
#pragma unroll
    for (int q = 0; q < 23; q++) ps += __expf((acc[q][j] + bq[q]) - pmax);
#pragma unroll
    for (int d = 1; d < 16; d <<= 1) ps += __shfl_xor(ps, d, 64);
    float lse = pmax + __logf(ps);

    int qm = mv >> 4, cm = mv & 15;
    float mlv = 0.f;
#pragma unroll
    for (int q = 0; q < 23; q++) if (q == qm) mlv = acc[q][j] + bq[q];
    mlv = __shfl(mlv, (l & 48) + cm, 64);
    float xent = lse - mlv;

    float amx = -3.0e38f; int aix = 0;
#pragma unroll
    for (int q = 0; q < 23; q++) {
      float v = acc[q][j] + bq[q];
      if (v > amx) { amx = v; aix = q * 16 + c; }
    }
#pragma unroll
    for (int d = 1; d < 16; d <<= 1) {
      float ov = __shfl_xor(amx, d, 64);
      int oi = __shfl_xor(aix, d, 64);
      if (ov > amx || (ov == amx && oi < aix)) { amx = ov; aix = oi; }
    }

    float pd = 0.f;
    int vrow = wm * 16 + rloc;
#pragma unroll
    for (int i = 0; i < 8; i++) {
      int k = c * 8 + i;
      short hv = *(short*)(sm + vrow * 256 + ((k * 2) ^ ((vrow & 7) << 4)));
      pd += b2f((unsigned short)hv) * Wv[k];
    }
#pragma unroll
    for (int d = 1; d < 16; d <<= 1) pd += __shfl_xor(pd, d, 64);
    float eo = __expf(2.f * (pd + bv[0]));
    float win = (eo - 1.f) * __builtin_amdgcn_rcpf(eo + 1.f);
    float dv = win - val;

    if (c == 0) {
      tp += msk * xent;
      tv += msk * dv * dv;
      ta += (aix == mv) ? 1.f : 0.f;
      tn += msk;
    }
  }
  tp += __shfl_xor(tp, 16, 64); tp += __shfl_xor(tp, 32, 64);
  tv += __shfl_xor(tv, 16, 64); tv += __shfl_xor(tv, 32, 64);
  ta += __shfl_xor(ta, 16, 64); ta += __shfl_xor(ta, 32, 64);
  tn += __shfl_xor(tn, 16, 64); tn += __shfl_xor(tn, 32, 64);
  if (l == 0) {
    atomicAdd(accum + 0, tp);
    atomicAdd(accum + 1, tv);
    atomicAdd(accum + 2, ta);
    atomicAdd(accum + 3, tn);
  }
}

__global__ void k_final(const float* __restrict__ accum, float* __restrict__ out) {
  if (threadIdx.x == 0) {
    float nm = accum[3];
    out[0] = accum[0] / nm;
    out[1] = accum[1] / nm;
    out[2] = accum[2] / 65536.0f;
  }
}

// --------------------------------------------------------------------------
extern "C" void kernel_launch(void* const* d_in, const int* in_sizes, int n_in,
                              void* d_out, int out_size, void* d_ws, size_t ws_size,
                              hipStream_t stream) {
  (void)in_sizes; (void)n_in; (void)out_size; (void)ws_size;
  const float* states = (const float*)d_in[0];
  const int*   moves  = (const int*)d_in[1];
  const float* values = (const float*)d_in[2];
  const float* W0 = (const float*)d_in[3];
  const float* b0 = (const float*)d_in[4];
  const float* W1 = (const float*)d_in[5];
  const float* b1 = (const float*)d_in[6];
  const float* Wp = (const float*)d_in[7];
  const float* bp = (const float*)d_in[8];
  const float* Wv = (const float*)d_in[9];
  const float* bv = (const float*)d_in[10];
  char* ws = (char*)d_ws;

  __hip_bfloat16* zbuf = (__hip_bfloat16*)(ws + OFF_Z);
  __hip_bfloat16* h1   = (__hip_bfloat16*)(ws + OFF_H1);
  __hip_bfloat16* W0xT = (__hip_bfloat16*)(ws + OFF_W0XT);
  __hip_bfloat16* WpT  = (__hip_bfloat16*)(ws + OFF_WPT);
  float* b0p = (float*)(ws + OFF_B0P);
  float* bpp = (float*)(ws + OFF_BPP);
  float* acc = (float*)(ws + OFF_ACC);

  k_conv_weights<<<956, 256, 0, stream>>>(W0, b0, Wp, bp, ws);
  k_gemm<KP0, true><<<dim3(512, 4), 256, 0, stream>>>(states, W0xT, b0p, zbuf);
  k_scan12<<<32, 1024, 0, stream>>>(zbuf, W0, W1, b1, h1);
  k_heads<<<1024, 256, 0, stream>>>(h1, WpT, bpp, Wv, bv, moves, values, acc);
  k_final<<<1, 1, 0, stream>>>(acc, (float*)d_out);
}

// Round 7
// 829.525 us; speedup vs baseline: 2.7890x; 1.2469x over previous
//
#include <hip/hip_runtime.h>
#include <hip/hip_bf16.h>
#include <stdint.h>

// ---------------------------------------------------------------------------
// RNN_79164837199890: 2-layer LSTM (B=128,T=512,H=128) + policy/value heads.
// R7: scan matmuls move to MX-scaled fp8 K=128 MFMA (scale=1.0):
// L0 = 4 MFMA/wave/step, L1 = 8 (was 16/32 of 16x16x32) at 2.3x rate.
// All-fp8 h exchange (bf16 h0 buffer deleted, LDS 8KB). Per-step h fp8
// encode via v_cvt_pk_fp8_f32 (1 op, was ~15). Geometry unchanged from R6:
// 32 WGs x 16 waves, roles L0/L1, one barrier per step, 513 steps.
// ---------------------------------------------------------------------------

typedef short v8s __attribute__((ext_vector_type(8)));   // 8 x bf16 fragment
typedef float v4f __attribute__((ext_vector_type(4)));   // MFMA accumulator
typedef int   v8i __attribute__((ext_vector_type(8)));   // 32 x fp8 fragment

#define MFMA_B16(a,b,c) __builtin_amdgcn_mfma_f32_16x16x32_bf16((a),(b),(c),0,0,0)
// K=128 fp8 MX MFMA, unit scales (e8m0 127 = 2^0)
#define MFMA_MX(a,b,c) \
  __builtin_amdgcn_mfma_scale_f32_16x16x128_f8f6f4((a),(b),(c),0,0,0,0x7F7F7F7F,0,0x7F7F7F7F)

#define NT     512
#define FIN    361
#define KP0    384        // padded K for layer-0 input GEMM
#define NPC    362
#define NPP    368

// workspace offsets (bytes)
#define OFF_Z    ((size_t)0)          // 65536*512*2 = 67108864 (z0x, gate-packed)
#define OFF_H1   ((size_t)83886080)   // 65536*128*2 = 16777216
#define OFF_W0XT ((size_t)100663296)  // 512*384*2 = 393216
#define OFF_WPT  ((size_t)101187584)  // 368*128*2 = 94208
#define OFF_B0P  ((size_t)101281792)  // 512*4 (pad 2048)
#define OFF_BPP  ((size_t)101285888)  // 368*4 (pad 2048)
#define OFF_ACC  ((size_t)101287936)  // 4 floats

static __device__ __forceinline__ short f2b(float f) {
  __hip_bfloat16 h = __float2bfloat16(f);
  union { __hip_bfloat16 h; short s; } cv; cv.h = h; return cv.s;
}
static __device__ __forceinline__ float b2f(unsigned int lo16) {
  union { unsigned u; float f; } cv; cv.u = lo16 << 16; return cv.f;
}
// f32 -> OCP e4m3fn with RNE (manual encode; used for one-time weight packs)
static __device__ __forceinline__ unsigned f2e4m3(float f) {
  union { float f; unsigned u; } cv; cv.f = f;
  unsigned s = (cv.u >> 31) << 7;
  float a = fabsf(f);
  a = fminf(a, 448.f);
  unsigned code;
  if (a >= 0.015625f) {                 // normal range: exp >= -6
    union { float f; unsigned u; } m; m.f = a;
    unsigned u = m.u + 0x7FFFF + ((m.u >> 20) & 1);   // RNE at 3 mantissa bits
    code = (u >> 20) - 960;             // rebias (127-7)<<3
    if (code > 126u) code = 126u;       // clamp to 448
  } else {                              // denormal: val = d * 2^-9
    code = (unsigned)rintf(a * 512.f);
  }
  return s | code;
}
// fast per-step fp8 encode (1 VALU op where available)
static __device__ __forceinline__ unsigned f2e4m3_fast(float f) {
#if __has_builtin(__builtin_amdgcn_cvt_pk_fp8_f32)
  return (unsigned)__builtin_amdgcn_cvt_pk_fp8_f32(f, f, 0, false) & 0xffu;
#else
  return f2e4m3(f);
#endif
}

// Raw barrier with LDS-only drain (global stores/loads keep floating).
static __device__ __forceinline__ void sync_lds() {
  __builtin_amdgcn_sched_barrier(0);
  asm volatile("s_waitcnt lgkmcnt(0)" ::: "memory");
  __builtin_amdgcn_s_barrier();
  __builtin_amdgcn_sched_barrier(0);
}

// --------------------------------------------------------------------------
// K0: weight conversion. Packed gate order: col' = m*4+g  <->  n = m + 128*g
// Forget-gate +1.0 folded into b0p. Zeroes accum.
// --------------------------------------------------------------------------
__global__ __launch_bounds__(256) void k_conv_weights(
    const float* __restrict__ W0, const float* __restrict__ b0,
    const float* __restrict__ Wp, const float* __restrict__ bp,
    char* __restrict__ ws) {
  int idx = blockIdx.x * 256 + threadIdx.x;
  __hip_bfloat16* W0xT = (__hip_bfloat16*)(ws + OFF_W0XT);
  __hip_bfloat16* WpT  = (__hip_bfloat16*)(ws + OFF_WPT);
  float* b0p = (float*)(ws + OFF_B0P);
  float* bpp = (float*)(ws + OFF_BPP);
  float* acc = (float*)(ws + OFF_ACC);

  if (idx < 196608) {                       // W0xT [512 cols'][384 k]
    int np = idx / 384, k = idx - np * 384;
    int n = (np >> 2) + 128 * (np & 3);
    float v = (k < FIN) ? W0[(size_t)k * 512 + n] : 0.f;
    W0xT[idx] = __float2bfloat16(v);
    return;
  }
  idx -= 196608;
  if (idx < 47104) {                        // WpT [368 p][128 k]
    int p = idx >> 7, k = idx & 127;
    WpT[idx] = __float2bfloat16(p < NPC ? Wp[(size_t)k * NPC + p] : 0.f);
    return;
  }
  idx -= 47104;
  if (idx < 512) {                          // b0p packed, +1.0 on forget gate
    int n = (idx >> 2) + 128 * (idx & 3);
    b0p[idx] = b0[n] + (((idx & 3) == 1) ? 1.0f : 0.0f);
    return;
  }
  idx -= 512;
  if (idx < NPP) { bpp[idx] = (idx < NPC) ? bp[idx] : -1e30f; return; }
  idx -= NPP;
  if (idx < 4) { acc[idx] = 0.f; return; }
}

// --------------------------------------------------------------------------
// K1: C[r, col'] = A[r,:] @ BT[col',:]^T + bias[col'],  C bf16 [65536][512]
// Tile 128x128, BK=64, 4 waves. AF32: A is f32 states with (b,t) remap and
// K-guard at 361.
// --------------------------------------------------------------------------
template<int KTOT, bool AF32>
__global__ __launch_bounds__(256) void k_gemm(
    const void* __restrict__ Ap, const __hip_bfloat16* __restrict__ BT,
    const float* __restrict__ bias, __hip_bfloat16* __restrict__ C) {
  __shared__ char sm[65536];                 // A: 2x16KB @0, B: 2x16KB @32768
  const int tid = threadIdx.x;
  const int l = tid & 63, wm = tid >> 6;
  const int c = l & 15, lg = l >> 4;
  const int m0 = blockIdx.x * 128;
  const int n0 = blockIdx.y * 128;
  constexpr int NS = KTOT / 64;

  uint4 ra[4], rb[4];
  float fa[32];

  auto LD = [&](int ks) {
#pragma unroll
    for (int i = 0; i < 4; i++) {
      int idx = i * 4096 + tid * 16;
      int row = idx >> 7, colb = idx & 127;
      if constexpr (AF32) {
        int r = m0 + row;
        const float* src = (const float*)Ap + ((size_t)(r & 127) * NT + (r >> 7)) * FIN;
        int kb = ks * 64 + (colb >> 1);
#pragma unroll
        for (int u = 0; u < 8; u++) {
          int kf = kb + u;
          fa[i * 8 + u] = (kf < FIN) ? src[kf] : 0.f;
        }
      } else {
        ra[i] = *(const uint4*)((const char*)Ap + ((size_t)(m0 + row) * KTOT + ks * 64) * 2 + colb);
      }
      rb[i] = *(const uint4*)((const char*)BT + ((size_t)(n0 + row) * KTOT + ks * 64) * 2 + colb);
    }
  };
  auto ST = [&](int bsel) {
#pragma unroll
    for (int i = 0; i < 4; i++) {
      int idx = i * 4096 + tid * 16;
      int row = idx >> 7, colb = idx & 127;
      int sw = colb ^ ((row & 7) << 4);
      if constexpr (AF32) {
        v8s w;
#pragma unroll
        for (int u = 0; u < 8; u++) w[u] = f2b(fa[i * 8 + u]);
        *(v8s*)(sm + bsel * 16384 + row * 128 + sw) = w;
      } else {
        *(uint4*)(sm + bsel * 16384 + row * 128 + sw) = ra[i];
      }
      *(uint4*)(sm + 32768 + bsel * 16384 + row * 128 + sw) = rb[i];
    }
  };

  v4f acc[2][8];
  v4f z4 = {0.f, 0.f, 0.f, 0.f};
#pragma unroll
  for (int mt = 0; mt < 2; mt++)
#pragma unroll
    for (int nt = 0; nt < 8; nt++) acc[mt][nt] = z4;

  LD(0); ST(0);
  __syncthreads();
  for (int ks = 0; ks < NS; ks++) {
    if (ks + 1 < NS) LD(ks + 1);
    const int bsel = ks & 1;
#pragma unroll
    for (int kk = 0; kk < 2; kk++) {
      int bir = kk * 64 + lg * 16;
      v8s af[2];
#pragma unroll
      for (int mt = 0; mt < 2; mt++) {
        int row = wm * 32 + mt * 16 + c;
        af[mt] = *(v8s*)(sm + bsel * 16384 + row * 128 + (bir ^ ((row & 7) << 4)));
      }
#pragma unroll
      for (int nt = 0; nt < 8; nt++) {
        int n = nt * 16 + c;
        v8s bf = *(v8s*)(sm + 32768 + bsel * 16384 + n * 128 + (bir ^ ((n & 7) << 4)));
#pragma unroll
        for (int mt = 0; mt < 2; mt++) acc[mt][nt] = MFMA_B16(af[mt], bf, acc[mt][nt]);
      }
    }
    if (ks + 1 < NS) ST((ks + 1) & 1);
    __syncthreads();
  }

#pragma unroll
  for (int mt = 0; mt < 2; mt++)
#pragma unroll
    for (int nt = 0; nt < 8; nt++) {
      int colp = n0 + nt * 16 + c;
      float bs = bias[colp];
#pragma unroll
      for (int j = 0; j < 4; j++) {
        int row = m0 + wm * 32 + mt * 16 + lg * 4 + j;
        C[(size_t)row * 512 + colp] = __float2bfloat16(acc[mt][nt][j] + bs);
      }
    }
}

// --------------------------------------------------------------------------
// K2: merged 2-layer scan, MX K=128 fp8. 32 WGs x 16 waves (1024 thr).
// chunk = 4 batch rows at M-rows {0,4,8,12}. role = wv>>3 (0: L0, 1: L1 one
// step behind). Wave rw owns hidden m in [16rw,16rw+16); lane (c,lg):
// m=16rw+c, batch=B0+lg (M-row 4lg). 1 cell/lane.
// LDS: h0 fp8 dbuf @0 (2x2KB), h1 fp8 dbuf @4096 (2x2KB). 8B-slot XOR
// swizzle (slot s of row r stored at s^r) — zero-conflict proven in R6.
// A-frag (K=128): lane (c,lg) reads row c, k = lg*32..lg*32+31 = slots
// (4lg+t)^c, t=0..3, as 4x ds_read_b64.
// --------------------------------------------------------------------------
__global__ __launch_bounds__(1024, 4) void k_scan12(
    const __hip_bfloat16* __restrict__ Z, const float* __restrict__ W0f,
    const float* __restrict__ W1f, const float* __restrict__ b1,
    __hip_bfloat16* __restrict__ h1out) {
  __shared__ char sm[8192];
  const int tid = threadIdx.x;
  const int l = tid & 63, wv = tid >> 6;
  const int c = l & 15, lg = l >> 4;
  const int role = wv >> 3, rw = wv & 7;
  const int B0 = blockIdx.x * 4;
  const int m_ = 16 * rw + c;
  const int row = 4 * lg;                    // M-row this lane's cell lives at
  v4f z4 = {0.f, 0.f, 0.f, 0.f};
  // fp8 h write offset (8B-slot XOR swizzle)
  const int wf8 = row * 128 + (((m_ >> 3) ^ row) << 3) + (m_ & 7);

  // zero LDS state (h0(-1)=h1(-1)=0; junk M-rows stay 0 forever)
  for (int e = tid * 4; e < 8192; e += 1024 * 4) *(int*)(sm + e) = 0;

  // A-frag loader: 32 fp8 from row c, k-range lg*32..+31 of a 2KB buffer
  auto AFRAG = [&](int base) -> v8i {
    union { unsigned long long q[4]; v8i v; } u;
#pragma unroll
    for (int t = 0; t < 4; t++)
      u.q[t] = *(const unsigned long long*)(
          sm + base + c * 128 + ((((lg * 4 + t) ^ c) & 15) << 3));
    return u.v;
  };

  if (role == 0) {
    // ================= L0 =================
    v8i breg[4];                             // fp8 W0h B-frags (32 VGPR)
#pragma unroll
    for (int g = 0; g < 4; g++) {
      int n = g * 128 + m_;
      union { unsigned long long q[4]; v8i v; } u;
#pragma unroll
      for (int t = 0; t < 4; t++) {
        unsigned long long w = 0ull;
#pragma unroll
        for (int j = 0; j < 8; j++) {
          int k = lg * 32 + t * 8 + j;
          w |= (unsigned long long)f2e4m3(W0f[(size_t)(FIN + k) * 512 + n]) << (8 * j);
        }
        u.q[t] = w;
      }
      breg[g] = u.v;
    }

    uint2 zA, zB, zC;
    auto ZLD = [&](int t) -> uint2 {
      return *(const uint2*)(Z + ((size_t)t * 128 + B0 + lg) * 512 + m_ * 4);
    };
    zA = ZLD(0); zB = ZLD(1);
    float cst = 0.f;
    __syncthreads();

    for (int s = 0; s < NT; s++) {
      v8i av = AFRAG(((s + 1) & 1) * 2048);  // h0(s-1) fp8
      v4f acc[4];
#pragma unroll
      for (int g = 0; g < 4; g++) acc[g] = z4;
#pragma unroll
      for (int g = 0; g < 4; g++) acc[g] = MFMA_MX(av, breg[g], acc[g]);
      if (s + 2 < NT) zC = ZLD(s + 2);

      float xi = acc[0][0] + b2f(zA.x & 0xffffu);
      float xf = acc[1][0] + b2f(zA.x >> 16);          // +1.0 folded into b0p
      float xg = acc[2][0] + b2f(zA.y & 0xffffu);
      float xo = acc[3][0] + b2f(zA.y >> 16);
      float ei = __expf(-xi);
      float ef = __expf(-xf);
      float eg = __expf(2.f * xg);
      float eo = __expf(-xo);
      float cn = cst * __builtin_amdgcn_rcpf(1.f + ef)
               + (eg - 1.f) * __builtin_amdgcn_rcpf((1.f + ei) * (eg + 1.f));
      cst = cn;
      float ec = __expf(2.f * cn);
      float hv = (ec - 1.f) * __builtin_amdgcn_rcpf((1.f + eo) * (ec + 1.f));
      *(unsigned char*)(sm + (s & 1) * 2048 + wf8) = (unsigned char)f2e4m3_fast(hv);
      zA = zB; zB = zC;
      sync_lds();
    }
    sync_lds();                                        // s = NT (L1 tail step)
  } else {
    // ================= L1 (one step behind) =================
    v8i bregH[4], bregX[4];                  // fp8 B-frags (64 VGPR)
#pragma unroll
    for (int g = 0; g < 4; g++) {
      int n = g * 128 + m_;
      union { unsigned long long q[4]; v8i v; } uh, ux;
#pragma unroll
      for (int t = 0; t < 4; t++) {
        unsigned long long wh = 0ull, wx = 0ull;
#pragma unroll
        for (int j = 0; j < 8; j++) {
          int k = lg * 32 + t * 8 + j;
          wh |= (unsigned long long)f2e4m3(W1f[(size_t)(128 + k) * 512 + n]) << (8 * j);
          wx |= (unsigned long long)f2e4m3(W1f[(size_t)k * 512 + n]) << (8 * j);
        }
        uh.q[t] = wh; ux.q[t] = wx;
      }
      bregH[g] = uh.v; bregX[g] = ux.v;
    }
    float bq[4];
#pragma unroll
    for (int g = 0; g < 4; g++)
      bq[g] = b1[g * 128 + m_] + ((g == 1) ? 1.0f : 0.0f);
    float cst = 0.f;
    __syncthreads();
    sync_lds();                                        // skip s=0 (idle)

    for (int s = 1; s <= NT; s++) {
      v8i ah = AFRAG(4096 + (s & 1) * 2048);           // h1(s-2) fp8
      v8i ax = AFRAG(((s + 1) & 1) * 2048);            // h0(s-1) fp8
      v4f acc[4];
#pragma unroll
      for (int g = 0; g < 4; g++) acc[g] = (v4f){bq[g], bq[g], bq[g], bq[g]};
#pragma unroll
      for (int g = 0; g < 4; g++) acc[g] = MFMA_MX(ah, bregH[g], acc[g]);
#pragma unroll
      for (int g = 0; g < 4; g++) acc[g] = MFMA_MX(ax, bregX[g], acc[g]);

      float xi = acc[0][0], xf = acc[1][0], xg = acc[2][0], xo = acc[3][0];
      float ei = __expf(-xi);
      float ef = __expf(-xf);
      float eg = __expf(2.f * xg);
      float eo = __expf(-xo);
      float cn = cst * __builtin_amdgcn_rcpf(1.f + ef)
               + (eg - 1.f) * __builtin_amdgcn_rcpf((1.f + ei) * (eg + 1.f));
      cst = cn;
      float ec = __expf(2.f * cn);
      float hv = (ec - 1.f) * __builtin_amdgcn_rcpf((1.f + eo) * (ec + 1.f));
      *(unsigned char*)(sm + 4096 + ((s + 1) & 1) * 2048 + wf8) =
          (unsigned char)f2e4m3_fast(hv);
      union { short s; __hip_bfloat16 h; } cv; cv.s = f2b(hv);
      h1out[((size_t)(s - 1) * 128 + B0 + lg) * 128 + m_] = cv.h;
      sync_lds();
    }
  }
}

// --------------------------------------------------------------------------
// K5: heads. WG = 64 rows (4 waves x 16). Logits GEMM [64x128]@[128x368] then
// per-row softmax/xent/argmax + value head; atomic partial sums.
// --------------------------------------------------------------------------
__global__ __launch_bounds__(256) void k_heads(
    const __hip_bfloat16* __restrict__ Hh, const __hip_bfloat16* __restrict__ WpT,
    const float* __restrict__ bpp, const float* __restrict__ Wv,
    const float* __restrict__ bv, const int* __restrict__ moves,
    const float* __restrict__ values, float* __restrict__ accum) {
  __shared__ char sm[110592];                // A 16KB @0, B 94208B @16384
  const int tid = threadIdx.x;
  const int l = tid & 63, wm = tid >> 6;
  const int c = l & 15, lg = l >> 4;
  const int r0 = blockIdx.x * 64;

#pragma unroll
  for (int i = 0; i < 4; i++) {
    int idx = i * 4096 + tid * 16;
    int row = idx >> 8, colb = idx & 255;
    uint4 v = *(const uint4*)((const char*)Hh + (size_t)r0 * 256 + idx);
    *(uint4*)(sm + row * 256 + (colb ^ ((row & 7) << 4))) = v;
  }
#pragma unroll
  for (int i = 0; i < 23; i++) {
    int idx = i * 4096 + tid * 16;
    int row = idx >> 8, colb = idx & 255;
    uint4 v = *(const uint4*)((const char*)WpT + idx);
    *(uint4*)(sm + 16384 + row * 256 + (colb ^ ((row & 7) << 4))) = v;
  }
  __syncthreads();

  v4f acc[23];
  v4f z4 = {0.f, 0.f, 0.f, 0.f};
#pragma unroll
  for (int q = 0; q < 23; q++) acc[q] = z4;
#pragma unroll
  for (int kk = 0; kk < 4; kk++) {
    int bir = kk * 64 + lg * 16;
    int ar = wm * 16 + c;
    v8s a = *(v8s*)(sm + ar * 256 + (bir ^ ((ar & 7) << 4)));
#pragma unroll
    for (int q = 0; q < 23; q++) {
      int n = q * 16 + c;
      v8s b = *(v8s*)(sm + 16384 + n * 256 + (bir ^ ((n & 7) << 4)));
      acc[q] = MFMA_B16(a, b, acc[q]);
    }
  }
  float bq[23];
#pragma unroll
  for (int q = 0; q < 23; q++) bq[q] = bpp[q * 16 + c];

  float tp = 0.f, tv = 0.f, ta = 0.f, tn = 0.f;
#pragma unroll
  for (int j = 0; j < 4; j++) {
    int rloc = lg * 4 + j;
    int r = r0 + wm * 16 + rloc;
    int t = r >> 7, b = r & 127;
    int mv = moves[(size_t)b * NT + t];
    float val = values[(size_t)b * NT + t];
    float msk = (val != -9.0f) ? 1.f : 0.f;

    float pmax = -3.0e38f;
#pragma unroll
    for (int q = 0; q < 23; q++) pmax = fmaxf(pmax, acc[q][j] + bq[q]);
#pragma unroll
    for (int d = 1; d < 16; d <<= 1) pmax = fmaxf(pmax, __shfl_xor(pmax, d, 64));
    float ps = 0.f;
#pragma unroll
    for (int q = 0; q < 23; q++) ps += __expf((acc[q][j] + bq[q]) - pmax);
#pragma unroll
    for (int d = 1; d < 16; d <<= 1) ps += __shfl_xor(ps, d, 64);
    float lse = pmax + __logf(ps);

    int qm = mv >> 4, cm = mv & 15;
    float mlv = 0.f;
#pragma unroll
    for (int q = 0; q < 23; q++) if (q == qm) mlv = acc[q][j] + bq[q];
    mlv = __shfl(mlv, (l & 48) + cm, 64);
    float xent = lse - mlv;

    float amx = -3.0e38f; int aix = 0;
#pragma unroll
    for (int q = 0; q < 23; q++) {
      float v = acc[q][j] + bq[q];
      if (v > amx) { amx = v; aix = q * 16 + c; }
    }
#pragma unroll
    for (int d = 1; d < 16; d <<= 1) {
      float ov = __shfl_xor(amx, d, 64);
      int oi = __shfl_xor(aix, d, 64);
      if (ov > amx || (ov == amx && oi < aix)) { amx = ov; aix = oi; }
    }

    float pd = 0.f;
    int vrow = wm * 16 + rloc;
#pragma unroll
    for (int i = 0; i < 8; i++) {
      int k = c * 8 + i;
      short hv = *(short*)(sm + vrow * 256 + ((k * 2) ^ ((vrow & 7) << 4)));
      pd += b2f((unsigned short)hv) * Wv[k];
    }
#pragma unroll
    for (int d = 1; d < 16; d <<= 1) pd += __shfl_xor(pd, d, 64);
    float eo = __expf(2.f * (pd + bv[0]));
    float win = (eo - 1.f) * __builtin_amdgcn_rcpf(eo + 1.f);
    float dv = win - val;

    if (c == 0) {
      tp += msk * xent;
      tv += msk * dv * dv;
      ta += (aix == mv) ? 1.f : 0.f;
      tn += msk;
    }
  }
  tp += __shfl_xor(tp, 16, 64); tp += __shfl_xor(tp, 32, 64);
  tv += __shfl_xor(tv, 16, 64); tv += __shfl_xor(tv, 32, 64);
  ta += __shfl_xor(ta, 16, 64); ta += __shfl_xor(ta, 32, 64);
  tn += __shfl_xor(tn, 16, 64); tn += __shfl_xor(tn, 32, 64);
  if (l == 0) {
    atomicAdd(accum + 0, tp);
    atomicAdd(accum + 1, tv);
    atomicAdd(accum + 2, ta);
    atomicAdd(accum + 3, tn);
  }
}

__global__ void k_final(const float* __restrict__ accum, float* __restrict__ out) {
  if (threadIdx.x == 0) {
    float nm = accum[3];
    out[0] = accum[0] / nm;
    out[1] = accum[1] / nm;
    out[2] = accum[2] / 65536.0f;
  }
}

// --------------------------------------------------------------------------
extern "C" void kernel_launch(void* const* d_in, const int* in_sizes, int n_in,
                              void* d_out, int out_size, void* d_ws, size_t ws_size,
                              hipStream_t stream) {
  (void)in_sizes; (void)n_in; (void)out_size; (void)ws_size;
  const float* states = (const float*)d_in[0];
  const int*   moves  = (const int*)d_in[1];
  const float* values = (const float*)d_in[2];
  const float* W0 = (const float*)d_in[3];
  const float* b0 = (const float*)d_in[4];
  const float* W1 = (const float*)d_in[5];
  const float* b1 = (const float*)d_in[6];
  const float* Wp = (const float*)d_in[7];
  const float* bp = (const float*)d_in[8];
  const float* Wv = (const float*)d_in[9];
  const float* bv = (const float*)d_in[10];
  char* ws = (char*)d_ws;

  __hip_bfloat16* zbuf = (__hip_bfloat16*)(ws + OFF_Z);
  __hip_bfloat16* h1   = (__hip_bfloat16*)(ws + OFF_H1);
  __hip_bfloat16* W0xT = (__hip_bfloat16*)(ws + OFF_W0XT);
  __hip_bfloat16* WpT  = (__hip_bfloat16*)(ws + OFF_WPT);
  float* b0p = (float*)(ws + OFF_B0P);
  float* bpp = (float*)(ws + OFF_BPP);
  float* acc = (float*)(ws + OFF_ACC);

  k_conv_weights<<<956, 256, 0, stream>>>(W0, b0, Wp, bp, ws);
  k_gemm<KP0, true><<<dim3(512, 4), 256, 0, stream>>>(states, W0xT, b0p, zbuf);
  k_scan12<<<32, 1024, 0, stream>>>(zbuf, W0, W1, b1, h1);
  k_heads<<<1024, 256, 0, stream>>>(h1, WpT, bpp, Wv, bv, moves, values, acc);
  k_final<<<1, 1, 0, stream>>>(acc, (float*)d_out);
}